// Round 2
// baseline (1678.015 us; speedup 1.0000x reference)
//
#include <hip/hip_runtime.h>
#include <cmath>

// Problem constants
#define NCH   256
#define NH    8
#define HD    32
#define NPIX  3136    // 56*56
#define NB    32
#define PT    64      // positions per block
#define INV_N (1.0f / 3136.0f)
#define LST   132     // LDS row stride (floats): mult-of-4 for f4 alignment

// ws layout (floats)
#define KV_FLOATS 262144              // kv[32][8][32][32]
#define KM_FLOATS 8192                // km[32][256]
#define WT_OFFSET (KV_FLOATS + KM_FLOATS)
#define WT_FLOATS (128 * 512)         // WT[k][c] = qk_w[c][k]

// ---------------------------------------------------------------------------
// Prep: transpose qk_w (512x128) -> WT (128x512) so GEMM reads are f4 rows.
// ---------------------------------------------------------------------------
__global__ void wt_kernel(const float* __restrict__ qk_w, float* __restrict__ WT) {
  const int k = blockIdx.x;       // 0..127
  const int t = threadIdx.x;      // 0..255
#pragma unroll
  for (int i = 0; i < 2; ++i) {
    const int c = t + 256 * i;
    WT[k * 512 + c] = qk_w[(size_t)c * 128 + k];
  }
}

// ---------------------------------------------------------------------------
// Kernel A: K = elu(Wk @ x1)+1 (conv from global/L2, 8ch x 8pos reg tile),
// then kv += K V^T and km += sum_p K via LDS-transposed tiles + atomics.
// Grid (49, 32), 256 threads.
// ---------------------------------------------------------------------------
__global__ __launch_bounds__(256)
void kv_kernel(const float* __restrict__ x, const float* __restrict__ WT,
               const float* __restrict__ qk_b, float* __restrict__ kv,
               float* __restrict__ km) {
  const int b = blockIdx.y;
  const int p0 = blockIdx.x * PT;
  const int t = threadIdx.x;
  const int chg = t >> 3, pg = t & 7;
  const int c0 = chg * 8, pq0 = pg * 8;

  __shared__ float KT[PT * LST];   // [pos][ch-local 0..127]
  __shared__ float VT[PT * LST];

  // ---- conv GEMM: K channels c0..c0+7, positions pq0..pq0+7 ----
  float acc[8][8];
#pragma unroll
  for (int i = 0; i < 8; ++i)
#pragma unroll
    for (int j = 0; j < 8; ++j) acc[i][j] = 0.f;

  const float* xk = x + ((size_t)(b * NCH + 128)) * NPIX + p0 + pq0;
  const float* wk = WT + 256 + c0;
#pragma unroll 2
  for (int k = 0; k < 128; ++k) {
    const float4 wa = *(const float4*)(wk + k * 512);
    const float4 wb = *(const float4*)(wk + k * 512 + 4);
    const float4 xa = *(const float4*)(xk + k * NPIX);
    const float4 xb = *(const float4*)(xk + k * NPIX + 4);
    const float wr[8] = {wa.x, wa.y, wa.z, wa.w, wb.x, wb.y, wb.z, wb.w};
    const float xr[8] = {xa.x, xa.y, xa.z, xa.w, xb.x, xb.y, xb.z, xb.w};
#pragma unroll
    for (int ci = 0; ci < 8; ++ci)
#pragma unroll
      for (int pi = 0; pi < 8; ++pi) acc[ci][pi] += wr[ci] * xr[pi];
  }

  // ---- bias + elu+1, km atomics from registers ----
  {
    const float4 ba = *(const float4*)(qk_b + 256 + c0);
    const float4 bb = *(const float4*)(qk_b + 256 + c0 + 4);
    const float br[8] = {ba.x, ba.y, ba.z, ba.w, bb.x, bb.y, bb.z, bb.w};
#pragma unroll
    for (int ci = 0; ci < 8; ++ci) {
      float s = 0.f;
#pragma unroll
      for (int pi = 0; pi < 8; ++pi) {
        float v = acc[ci][pi] + br[ci];
        v = (v > 0.f) ? (v + 1.f) : __expf(v);
        acc[ci][pi] = v;
        s += v;
      }
      atomicAdd(&km[b * NCH + c0 + ci], s);
    }
  }

  // ---- per 4-head group: stage K^T, V^T; kv outer-product accumulate ----
  const int h_l = t >> 6;
  const int s5 = t & 63;
  const int dg = s5 >> 3, eg = s5 & 7;

  for (int hg = 0; hg < 2; ++hg) {
    __syncthreads();
    // V^T staging (all threads): coalesced f4 global read, padded transpose
#pragma unroll
    for (int r = 0; r < 8; ++r) {
      const int id = t + 256 * r;          // 0..2047
      const int cc = id >> 4;              // 0..127
      const int pp0 = (id & 15) * 4;
      const float4 v = *(const float4*)(
          x + ((size_t)(b * NCH + hg * 128 + cc)) * NPIX + p0 + pp0);
      VT[(pp0 + 0) * LST + cc] = v.x;
      VT[(pp0 + 1) * LST + cc] = v.y;
      VT[(pp0 + 2) * LST + cc] = v.z;
      VT[(pp0 + 3) * LST + cc] = v.w;
    }
    // K^T staging: threads owning this group's channels
    if ((chg >> 4) == hg) {
      const int lc0 = (chg & 15) * 8;
#pragma unroll
      for (int j = 0; j < 8; ++j) {
        const float4 lo = {acc[0][j], acc[1][j], acc[2][j], acc[3][j]};
        const float4 hi = {acc[4][j], acc[5][j], acc[6][j], acc[7][j]};
        *(float4*)(KT + (pq0 + j) * LST + lc0) = lo;
        *(float4*)(KT + (pq0 + j) * LST + lc0 + 4) = hi;
      }
    }
    __syncthreads();

    // kv: thread = (head h_l, 4d, 4e); per p: 2 f4 LDS (conflict-free) + 16 FMA
    float kvp[4][4];
#pragma unroll
    for (int i = 0; i < 4; ++i)
#pragma unroll
      for (int j = 0; j < 4; ++j) kvp[i][j] = 0.f;
#pragma unroll 4
    for (int p = 0; p < PT; ++p) {
      const float4 kf = *(const float4*)(KT + p * LST + h_l * 32 + dg * 4);
      const float4 vf = *(const float4*)(VT + p * LST + h_l * 32 + eg * 4);
      const float kr[4] = {kf.x, kf.y, kf.z, kf.w};
      const float vr[4] = {vf.x, vf.y, vf.z, vf.w};
#pragma unroll
      for (int di = 0; di < 4; ++di)
#pragma unroll
        for (int ei = 0; ei < 4; ++ei) kvp[di][ei] += kr[di] * vr[ei];
    }
    const int h = hg * 4 + h_l;
    float* kvdst = kv + (((size_t)b * NH + h) * HD + dg * 4) * HD + eg * 4;
#pragma unroll
    for (int di = 0; di < 4; ++di)
#pragma unroll
      for (int ei = 0; ei < 4; ++ei)
        atomicAdd(kvdst + di * HD + ei, kvp[di][ei]);
  }
}

// ---------------------------------------------------------------------------
// Kernel B: Q = elu(Wq @ x0)+1 (same direct-global conv), then
// out = (Q^T kv')/(Q^T km' + eps) + pe(x).  Grid (49, 32), 256 threads.
// ---------------------------------------------------------------------------
__global__ __launch_bounds__(256)
void out_kernel(const float* __restrict__ x, const float* __restrict__ WT,
                const float* __restrict__ qk_b, const float* __restrict__ pe_w,
                const float* __restrict__ pe_b, const float* __restrict__ kvg,
                const float* __restrict__ kmg, float* __restrict__ out) {
  const int b = blockIdx.y;
  const int p0 = blockIdx.x * PT;
  const int t = threadIdx.x;
  const int chg = t >> 3, pg = t & 7;
  const int c0 = chg * 8, pq0 = pg * 8;

  __shared__ float QT[PT * LST];       // [pos][q-ch local 0..127]
  __shared__ float kvs[4 * 32 * 32];   // this group's kv, pre-scaled
  __shared__ float kms[128];           // this group's kmean, pre-scaled

  // ---- conv GEMM for Q ----
  float acc[8][8];
#pragma unroll
  for (int i = 0; i < 8; ++i)
#pragma unroll
    for (int j = 0; j < 8; ++j) acc[i][j] = 0.f;

  const float* xk = x + ((size_t)b * NCH) * NPIX + p0 + pq0;
  const float* wk = WT + c0;
#pragma unroll 2
  for (int k = 0; k < 128; ++k) {
    const float4 wa = *(const float4*)(wk + k * 512);
    const float4 wb = *(const float4*)(wk + k * 512 + 4);
    const float4 xa = *(const float4*)(xk + k * NPIX);
    const float4 xb = *(const float4*)(xk + k * NPIX + 4);
    const float wr[8] = {wa.x, wa.y, wa.z, wa.w, wb.x, wb.y, wb.z, wb.w};
    const float xr[8] = {xa.x, xa.y, xa.z, xa.w, xb.x, xb.y, xb.z, xb.w};
#pragma unroll
    for (int ci = 0; ci < 8; ++ci)
#pragma unroll
      for (int pi = 0; pi < 8; ++pi) acc[ci][pi] += wr[ci] * xr[pi];
  }
  {
    const float4 ba = *(const float4*)(qk_b + c0);
    const float4 bb = *(const float4*)(qk_b + c0 + 4);
    const float br[8] = {ba.x, ba.y, ba.z, ba.w, bb.x, bb.y, bb.z, bb.w};
#pragma unroll
    for (int ci = 0; ci < 8; ++ci)
#pragma unroll
      for (int pi = 0; pi < 8; ++pi) {
        float v = acc[ci][pi] + br[ci];
        acc[ci][pi] = (v > 0.f) ? (v + 1.f) : __expf(v);
      }
  }

  // num-phase mapping: interleaved positions (pg2 + 8j) for conflict-free QT
  const int h_l = t >> 6;
  const int s5 = t & 63;
  const int eg = s5 >> 3, pg2 = s5 & 7;

  for (int hg = 0; hg < 2; ++hg) {
    __syncthreads();
    // stage kv' (flat 4096 floats) and km'
    {
      const float4* src = (const float4*)(kvg + ((size_t)b * NH + hg * 4) * HD * HD);
      float4* dst = (float4*)kvs;
#pragma unroll
      for (int r = 0; r < 4; ++r) {
        const int id = t + 256 * r;
        float4 v = src[id];
        v.x *= INV_N; v.y *= INV_N; v.z *= INV_N; v.w *= INV_N;
        dst[id] = v;
      }
      if (t < 128) kms[t] = kmg[b * NCH + hg * 128 + t] * INV_N;
    }
    // stage Q^T
    if ((chg >> 4) == hg) {
      const int lc0 = (chg & 15) * 8;
#pragma unroll
      for (int j = 0; j < 8; ++j) {
        const float4 lo = {acc[0][j], acc[1][j], acc[2][j], acc[3][j]};
        const float4 hi = {acc[4][j], acc[5][j], acc[6][j], acc[7][j]};
        *(float4*)(QT + (pq0 + j) * LST + lc0) = lo;
        *(float4*)(QT + (pq0 + j) * LST + lc0 + 4) = hi;
      }
    }
    __syncthreads();

    // num/den: thread = (head h_l, 4e = 4*eg, 8 pos = pg2+8j), d-blocked by 4
    float nacc[4][8];
#pragma unroll
    for (int i = 0; i < 4; ++i)
#pragma unroll
      for (int j = 0; j < 8; ++j) nacc[i][j] = 0.f;
    float den[8];
#pragma unroll
    for (int j = 0; j < 8; ++j) den[j] = 0.f;

#pragma unroll 2
    for (int dq = 0; dq < 8; ++dq) {
      float4 kvv[4];
#pragma unroll
      for (int di = 0; di < 4; ++di)
        kvv[di] = *(const float4*)(kvs + (h_l * 32 + dq * 4 + di) * 32 + eg * 4);
      const float4 kmv = *(const float4*)(kms + h_l * 32 + dq * 4);
      const float kmr[4] = {kmv.x, kmv.y, kmv.z, kmv.w};
#pragma unroll
      for (int j = 0; j < 8; ++j) {
        const float4 q4 = *(const float4*)(QT + (pg2 + 8 * j) * LST + h_l * 32 + dq * 4);
        const float qr[4] = {q4.x, q4.y, q4.z, q4.w};
#pragma unroll
        for (int di = 0; di < 4; ++di) {
          den[j] += qr[di] * kmr[di];
          nacc[0][j] += qr[di] * kvv[di].x;
          nacc[1][j] += qr[di] * kvv[di].y;
          nacc[2][j] += qr[di] * kvv[di].z;
          nacc[3][j] += qr[di] * kvv[di].w;
        }
      }
    }
    float rden[8];
#pragma unroll
    for (int j = 0; j < 8; ++j) rden[j] = 1.0f / (den[j] + 1e-6f);

    // pe + write: out channel c = hg*128 + h_l*32 + 4*eg + ei, pos p0+pg2+8j
#pragma unroll
    for (int ei = 0; ei < 4; ++ei) {
      const int c = hg * 128 + h_l * 32 + eg * 4 + ei;
      const float* pw = pe_w + c * 9;
      const float peb = pe_b[c];
      const float* xc = x + ((size_t)(b * NCH + c)) * NPIX;
      float* oc = out + ((size_t)(b * NCH + c)) * NPIX;
#pragma unroll
      for (int j = 0; j < 8; ++j) {
        const int pabs = p0 + pg2 + 8 * j;
        const int r = pabs / 56;
        const int cl = pabs - r * 56;
        float s = peb;
#pragma unroll
        for (int dy = -1; dy <= 1; ++dy) {
          const int rr = r + dy;
          if (rr < 0 || rr >= 56) continue;
#pragma unroll
          for (int dx = -1; dx <= 1; ++dx) {
            const int cc = cl + dx;
            if (cc < 0 || cc >= 56) continue;
            s += pw[(dy + 1) * 3 + (dx + 1)] * xc[rr * 56 + cc];
          }
        }
        oc[pabs] = nacc[ei][j] * rden[j] + s;
      }
    }
  }
}

extern "C" void kernel_launch(void* const* d_in, const int* in_sizes, int n_in,
                              void* d_out, int out_size, void* d_ws,
                              size_t ws_size, hipStream_t stream) {
  const float* x    = (const float*)d_in[0];
  const float* qk_w = (const float*)d_in[1];
  const float* qk_b = (const float*)d_in[2];
  const float* pe_w = (const float*)d_in[3];
  const float* pe_b = (const float*)d_in[4];
  float* out = (float*)d_out;
  float* kv  = (float*)d_ws;
  float* km  = kv + KV_FLOATS;
  float* WT  = kv + WT_OFFSET;

  // zero the atomic accumulators every launch (harness doesn't re-poison)
  hipMemsetAsync(d_ws, 0, (KV_FLOATS + KM_FLOATS) * sizeof(float), stream);

  wt_kernel<<<128, 256, 0, stream>>>(qk_w, WT);

  dim3 g(49, NB);
  kv_kernel<<<g, 256, 0, stream>>>(x, WT, qk_b, kv, km);
  out_kernel<<<g, 256, 0, stream>>>(x, WT, qk_b, pe_w, pe_b, kv, km, out);
}

// Round 3
// 711.167 us; speedup vs baseline: 2.3595x; 2.3595x over previous
//
#include <hip/hip_runtime.h>
#include <cmath>

// Problem constants
#define NCH   256
#define NH    8
#define HD    32
#define NPIX  3136    // 56*56
#define NB    32
#define INV_N (1.0f / 3136.0f)
#define LST   132     // LDS row stride for QT (floats)

// ws layout (floats)
#define KV2_FLOATS (2 * NB * NH * HD * HD)   // 524288 (2 MB)
#define KM2_FLOATS (2 * NB * NH * HD)        // 16384
#define WT_OFFSET  (KV2_FLOATS + KM2_FLOATS)
#define WT_FLOATS  (128 * 512)               // WT[k][c] = qk_w[c][k]

// ---------------------------------------------------------------------------
// Prep: transpose qk_w (512x128) -> WT (128x512).
// ---------------------------------------------------------------------------
__global__ void wt_kernel(const float* __restrict__ qk_w, float* __restrict__ WT) {
  const int k = blockIdx.x;
  const int t = threadIdx.x;
#pragma unroll
  for (int i = 0; i < 2; ++i) {
    const int c = t + 256 * i;
    WT[k * 512 + c] = qk_w[(size_t)c * 128 + k];
  }
}

// ---------------------------------------------------------------------------
// Kernel A: per (b, head, half): conv K for 32 channels over 1568 positions
// (13 tiles of 128), accumulate kv[32][32] in registers across tiles,
// reduce across waves in LDS, write disjoint partials. NO global atomics.
// Grid (16, 32): blockIdx.x = h + 8*s, blockIdx.y = b. 256 threads.
// ---------------------------------------------------------------------------
__global__ __launch_bounds__(256)
void kv_kernel(const float* __restrict__ x, const float* __restrict__ WT,
               const float* __restrict__ qk_b, float* __restrict__ kv2,
               float* __restrict__ km2) {
  const int h = blockIdx.x & 7;
  const int s = blockIdx.x >> 3;
  const int b = blockIdx.y;
  const int t = threadIdx.x;
  const int chg = t >> 5;          // 0..7 -> 4 channels each
  const int pg  = t & 31;          // f4-position within tile
  const int wave = t >> 6, lane = t & 63;
  const int dg = lane >> 3, eg = lane & 7;

  __shared__ float KT[128][36];    // [pos][ch-local], +4 pad
  __shared__ float VT[128][36];
  __shared__ float red[4][1024];   // cross-wave kv reduction
  __shared__ float kmred[32];

  float kvacc[4][4];
#pragma unroll
  for (int i = 0; i < 4; ++i)
#pragma unroll
    for (int j = 0; j < 4; ++j) kvacc[i][j] = 0.f;
  float kmacc[4] = {0.f, 0.f, 0.f, 0.f};

  const float* wk = WT + 256 + h * HD + chg * 4;                      // +k*512
  const float* xk = x + ((size_t)(b * NCH + 128)) * NPIX + s * 1568;  // conv in
  const float* xv = x + ((size_t)(b * NCH + h * HD)) * NPIX + s * 1568;  // V
  const float4 b4 = *(const float4*)(qk_b + 256 + h * HD + chg * 4);
  const float br[4] = {b4.x, b4.y, b4.z, b4.w};

  for (int tile = 0; tile < 13; ++tile) {
    const int p0 = tile * 128;
    const int L = (tile == 12) ? 32 : 128;
    const bool act = (pg * 4 < L);

    // ---- conv: 4ch x 4pos register tile ----
    float a[4][4];
#pragma unroll
    for (int i = 0; i < 4; ++i)
#pragma unroll
      for (int j = 0; j < 4; ++j) a[i][j] = 0.f;
    if (act) {
      const float* xp = xk + p0 + pg * 4;
#pragma unroll 4
      for (int k = 0; k < 128; ++k) {
        const float4 w4 = *(const float4*)(wk + k * 512);
        const float4 x4 = *(const float4*)(xp + (size_t)k * NPIX);
        const float wr[4] = {w4.x, w4.y, w4.z, w4.w};
        const float xr[4] = {x4.x, x4.y, x4.z, x4.w};
#pragma unroll
        for (int ci = 0; ci < 4; ++ci)
#pragma unroll
          for (int pi = 0; pi < 4; ++pi) a[ci][pi] += wr[ci] * xr[pi];
      }
    }

    __syncthreads();  // previous tile's LDS fully consumed

    // ---- bias + elu+1, km partial, stage K^T ----
    if (act) {
#pragma unroll
      for (int pi = 0; pi < 4; ++pi) {
        float kv4[4];
#pragma unroll
        for (int ci = 0; ci < 4; ++ci) {
          float v = a[ci][pi] + br[ci];
          v = (v > 0.f) ? (v + 1.f) : __expf(v);
          kmacc[ci] += v;
          kv4[ci] = v;
        }
        *(float4*)&KT[pg * 4 + pi][chg * 4] =
            make_float4(kv4[0], kv4[1], kv4[2], kv4[3]);
      }
    }
    // ---- stage V^T (coalesced f4 reads, scalar transpose writes) ----
#pragma unroll
    for (int rr = 0; rr < 4; ++rr) {
      const int id = t + 256 * rr;     // 0..1023 = 32ch x 32 f4-pos
      const int cc = id >> 5;
      const int pf = id & 31;
      if (pf * 4 < L) {
        const float4 v = *(const float4*)(xv + (size_t)cc * NPIX + p0 + pf * 4);
        VT[pf * 4 + 0][cc] = v.x;
        VT[pf * 4 + 1][cc] = v.y;
        VT[pf * 4 + 2][cc] = v.z;
        VT[pf * 4 + 3][cc] = v.w;
      }
    }
    __syncthreads();

    // ---- kv accumulate: wave w owns positions [w*32, w*32+32) of tile ----
    const int pw1 = min(wave * 32 + 32, L);
    for (int p = wave * 32; p < pw1; ++p) {
      const float4 kf = *(const float4*)&KT[p][dg * 4];
      const float4 vf = *(const float4*)&VT[p][eg * 4];
      const float kr[4] = {kf.x, kf.y, kf.z, kf.w};
      const float vr[4] = {vf.x, vf.y, vf.z, vf.w};
#pragma unroll
      for (int di = 0; di < 4; ++di)
#pragma unroll
        for (int ei = 0; ei < 4; ++ei) kvacc[di][ei] += kr[di] * vr[ei];
    }
  }

  // ---- final reduce: 4 waves -> kv2 partial; km via LDS atomics ----
  if (t < 32) kmred[t] = 0.f;
#pragma unroll
  for (int di = 0; di < 4; ++di)
#pragma unroll
    for (int ei = 0; ei < 4; ++ei)
      red[wave][(dg * 4 + di) * 32 + eg * 4 + ei] = kvacc[di][ei];
  __syncthreads();

  float* kvdst = kv2 + (((size_t)s * NB + b) * NH + h) * 1024;
#pragma unroll
  for (int i = 0; i < 4; ++i) {
    const int e = t + 256 * i;
    kvdst[e] = red[0][e] + red[1][e] + red[2][e] + red[3][e];
  }
#pragma unroll
  for (int ci = 0; ci < 4; ++ci) atomicAdd(&kmred[chg * 4 + ci], kmacc[ci]);
  __syncthreads();
  if (t < 32) km2[(((size_t)s * NB + b) * NH + h) * HD + t] = kmred[t];
}

// ---------------------------------------------------------------------------
// Kernel B: Q = elu(Wq @ x0)+1, out = (Q^T kv')/(Q^T km' + eps).
// (pe added by a separate kernel.) Grid (49, 32), 256 threads.
// ---------------------------------------------------------------------------
__global__ __launch_bounds__(256)
void out_kernel(const float* __restrict__ x, const float* __restrict__ WT,
                const float* __restrict__ qk_b, const float* __restrict__ kv2,
                const float* __restrict__ km2, float* __restrict__ out) {
  const int b = blockIdx.y;
  const int p0 = blockIdx.x * 64;
  const int t = threadIdx.x;
  const int chg = t >> 3, pg = t & 7;
  const int c0 = chg * 8, pq0 = pg * 8;

  __shared__ float QT[64 * LST];
  __shared__ float kvs[4 * 32 * 32];
  __shared__ float kms[128];

  // ---- conv GEMM for Q: 8ch x 8pos register tile ----
  float acc[8][8];
#pragma unroll
  for (int i = 0; i < 8; ++i)
#pragma unroll
    for (int j = 0; j < 8; ++j) acc[i][j] = 0.f;

  const float* xk = x + ((size_t)b * NCH) * NPIX + p0 + pq0;
  const float* wk = WT + c0;
#pragma unroll 4
  for (int k = 0; k < 128; ++k) {
    const float4 wa = *(const float4*)(wk + k * 512);
    const float4 wb = *(const float4*)(wk + k * 512 + 4);
    const float4 xa = *(const float4*)(xk + (size_t)k * NPIX);
    const float4 xb = *(const float4*)(xk + (size_t)k * NPIX + 4);
    const float wr[8] = {wa.x, wa.y, wa.z, wa.w, wb.x, wb.y, wb.z, wb.w};
    const float xr[8] = {xa.x, xa.y, xa.z, xa.w, xb.x, xb.y, xb.z, xb.w};
#pragma unroll
    for (int ci = 0; ci < 8; ++ci)
#pragma unroll
      for (int pi = 0; pi < 8; ++pi) acc[ci][pi] += wr[ci] * xr[pi];
  }
  {
    const float4 ba = *(const float4*)(qk_b + c0);
    const float4 bb = *(const float4*)(qk_b + c0 + 4);
    const float br[8] = {ba.x, ba.y, ba.z, ba.w, bb.x, bb.y, bb.z, bb.w};
#pragma unroll
    for (int ci = 0; ci < 8; ++ci)
#pragma unroll
      for (int pi = 0; pi < 8; ++pi) {
        float v = acc[ci][pi] + br[ci];
        acc[ci][pi] = (v > 0.f) ? (v + 1.f) : __expf(v);
      }
  }

  const int h_l = t >> 6;
  const int s5 = t & 63;
  const int eg = s5 >> 3, pg2 = s5 & 7;

  for (int hg = 0; hg < 2; ++hg) {
    __syncthreads();
    // stage kv' (sum of the two halves) and km'
    {
      const float4* s0 = (const float4*)(kv2 + ((size_t)(0 * NB + b) * NH + hg * 4) * 1024);
      const float4* s1 = (const float4*)(kv2 + ((size_t)(1 * NB + b) * NH + hg * 4) * 1024);
      float4* dst = (float4*)kvs;
#pragma unroll
      for (int r = 0; r < 4; ++r) {
        const int id = t + 256 * r;
        const float4 u = s0[id];
        const float4 w = s1[id];
        dst[id] = make_float4((u.x + w.x) * INV_N, (u.y + w.y) * INV_N,
                              (u.z + w.z) * INV_N, (u.w + w.w) * INV_N);
      }
      if (t < 128) {
        const int hh = hg * 4 + (t >> 5), cc = t & 31;
        kms[t] = (km2[((size_t)(0 * NB + b) * NH + hh) * HD + cc] +
                  km2[((size_t)(1 * NB + b) * NH + hh) * HD + cc]) * INV_N;
      }
    }
    // stage Q^T for this head-group's 128 channels
    if ((chg >> 4) == hg) {
      const int lc0 = (chg & 15) * 8;
#pragma unroll
      for (int j = 0; j < 8; ++j) {
        const float4 lo = {acc[0][j], acc[1][j], acc[2][j], acc[3][j]};
        const float4 hi = {acc[4][j], acc[5][j], acc[6][j], acc[7][j]};
        *(float4*)(QT + (pq0 + j) * LST + lc0) = lo;
        *(float4*)(QT + (pq0 + j) * LST + lc0 + 4) = hi;
      }
    }
    __syncthreads();

    // num/den: thread = (head h_l, 4e, 8 interleaved pos)
    float nacc[4][8];
#pragma unroll
    for (int i = 0; i < 4; ++i)
#pragma unroll
      for (int j = 0; j < 8; ++j) nacc[i][j] = 0.f;
    float den[8];
#pragma unroll
    for (int j = 0; j < 8; ++j) den[j] = 0.f;

#pragma unroll 2
    for (int dq = 0; dq < 8; ++dq) {
      float4 kvv[4];
#pragma unroll
      for (int di = 0; di < 4; ++di)
        kvv[di] = *(const float4*)(kvs + (h_l * 32 + dq * 4 + di) * 32 + eg * 4);
      const float4 kmv = *(const float4*)(kms + h_l * 32 + dq * 4);
      const float kmr[4] = {kmv.x, kmv.y, kmv.z, kmv.w};
#pragma unroll
      for (int j = 0; j < 8; ++j) {
        const float4 q4 = *(const float4*)(QT + (pg2 + 8 * j) * LST + h_l * 32 + dq * 4);
        const float qr[4] = {q4.x, q4.y, q4.z, q4.w};
#pragma unroll
        for (int di = 0; di < 4; ++di) {
          den[j] += qr[di] * kmr[di];
          nacc[0][j] += qr[di] * kvv[di].x;
          nacc[1][j] += qr[di] * kvv[di].y;
          nacc[2][j] += qr[di] * kvv[di].z;
          nacc[3][j] += qr[di] * kvv[di].w;
        }
      }
    }
#pragma unroll
    for (int ei = 0; ei < 4; ++ei) {
      const int c = hg * 128 + h_l * 32 + eg * 4 + ei;
      float* oc = out + ((size_t)(b * NCH + c)) * NPIX;
#pragma unroll
      for (int j = 0; j < 8; ++j) {
        const int pabs = p0 + pg2 + 8 * j;
        oc[pabs] = nacc[ei][j] / (den[j] + 1e-6f);
      }
    }
  }
}

// ---------------------------------------------------------------------------
// Kernel C: depthwise 3x3 pe conv, added into out (RMW). One thread per
// (channel, row), sliding float4 window along the row.
// Grid (64, 32): channels blockIdx.x*4 + t>>6, batch = blockIdx.y.
// ---------------------------------------------------------------------------
__global__ __launch_bounds__(256)
void pe_kernel(const float* __restrict__ x, const float* __restrict__ pe_w,
               const float* __restrict__ pe_b, float* __restrict__ out) {
  const int b = blockIdx.y;
  const int c = blockIdx.x * 4 + (threadIdx.x >> 6);
  const int r = threadIdx.x & 63;
  if (r >= 56) return;

  const float* xc = x + ((size_t)(b * NCH + c)) * NPIX;
  float* oc = out + ((size_t)(b * NCH + c)) * NPIX + r * 56;

  float pw[9];
#pragma unroll
  for (int i = 0; i < 9; ++i) pw[i] = pe_w[c * 9 + i];
  const float pb = pe_b[c];

  const bool hasU = (r > 0), hasD = (r < 55);
  const float* rowU = xc + (r - 1) * 56;
  const float* row0 = xc + r * 56;
  const float* rowD = xc + (r + 1) * 56;
  const float4 Z = {0.f, 0.f, 0.f, 0.f};

  // window covers cols [p0-4, p0+12)
  float4 um[4], u0[4], ud[4];
  um[0] = Z; u0[0] = Z; ud[0] = Z;
#pragma unroll
  for (int k = 1; k < 4; ++k) {
    const int col = (k - 1) * 4;
    um[k] = hasU ? *(const float4*)(rowU + col) : Z;
    u0[k] = *(const float4*)(row0 + col);
    ud[k] = hasD ? *(const float4*)(rowD + col) : Z;
  }

  for (int jc = 0; jc < 7; ++jc) {
    const int p0 = jc * 8;
    float wm[16], w0[16], wd[16];
#pragma unroll
    for (int k = 0; k < 4; ++k) {
      wm[4 * k] = um[k].x; wm[4 * k + 1] = um[k].y; wm[4 * k + 2] = um[k].z; wm[4 * k + 3] = um[k].w;
      w0[4 * k] = u0[k].x; w0[4 * k + 1] = u0[k].y; w0[4 * k + 2] = u0[k].z; w0[4 * k + 3] = u0[k].w;
      wd[4 * k] = ud[k].x; wd[4 * k + 1] = ud[k].y; wd[4 * k + 2] = ud[k].z; wd[4 * k + 3] = ud[k].w;
    }
    float res[8];
#pragma unroll
    for (int p = 0; p < 8; ++p) {
      float s = pb;
      s += pw[0] * wm[3 + p] + pw[1] * wm[4 + p] + pw[2] * wm[5 + p];
      s += pw[3] * w0[3 + p] + pw[4] * w0[4 + p] + pw[5] * w0[5 + p];
      s += pw[6] * wd[3 + p] + pw[7] * wd[4 + p] + pw[8] * wd[5 + p];
      res[p] = s;
    }
    float4 o0 = *(const float4*)(oc + p0);
    float4 o1 = *(const float4*)(oc + p0 + 4);
    o0.x += res[0]; o0.y += res[1]; o0.z += res[2]; o0.w += res[3];
    o1.x += res[4]; o1.y += res[5]; o1.z += res[6]; o1.w += res[7];
    *(float4*)(oc + p0) = o0;
    *(float4*)(oc + p0 + 4) = o1;

    if (jc < 6) {
      um[0] = um[2]; um[1] = um[3];
      u0[0] = u0[2]; u0[1] = u0[3];
      ud[0] = ud[2]; ud[1] = ud[3];
      const int cA = p0 + 12, cB = p0 + 16;
      const bool okB = (cB < 56);
      um[2] = hasU ? *(const float4*)(rowU + cA) : Z;
      u0[2] = *(const float4*)(row0 + cA);
      ud[2] = hasD ? *(const float4*)(rowD + cA) : Z;
      um[3] = (hasU && okB) ? *(const float4*)(rowU + cB) : Z;
      u0[3] = okB ? *(const float4*)(row0 + cB) : Z;
      ud[3] = (hasD && okB) ? *(const float4*)(rowD + cB) : Z;
    }
  }
}

extern "C" void kernel_launch(void* const* d_in, const int* in_sizes, int n_in,
                              void* d_out, int out_size, void* d_ws,
                              size_t ws_size, hipStream_t stream) {
  const float* x    = (const float*)d_in[0];
  const float* qk_w = (const float*)d_in[1];
  const float* qk_b = (const float*)d_in[2];
  const float* pe_w = (const float*)d_in[3];
  const float* pe_b = (const float*)d_in[4];
  float* out = (float*)d_out;
  float* kv2 = (float*)d_ws;
  float* km2 = kv2 + KV2_FLOATS;
  float* WT  = kv2 + WT_OFFSET;

  wt_kernel<<<128, 256, 0, stream>>>(qk_w, WT);

  dim3 g1(16, NB);
  kv_kernel<<<g1, 256, 0, stream>>>(x, WT, qk_b, kv2, km2);

  dim3 g2(49, NB);
  out_kernel<<<g2, 256, 0, stream>>>(x, WT, qk_b, kv2, km2, out);

  dim3 g3(64, NB);
  pe_kernel<<<g3, 256, 0, stream>>>(x, pe_w, pe_b, out);
}

// Round 4
// 563.349 us; speedup vs baseline: 2.9786x; 1.2624x over previous
//
#include <hip/hip_runtime.h>
#include <cmath>

// Problem constants
#define NCH   256
#define NH    8
#define HD    32
#define NPIX  3136    // 56*56
#define NB    32
#define INV_N (1.0f / 3136.0f)

// ws layout (floats)
#define KV2_FLOATS (2 * NB * NH * HD * HD)   // 524288 (2 MB)
#define KM2_FLOATS (2 * NB * NH * HD)        // 16384
#define WT_OFFSET  (KV2_FLOATS + KM2_FLOATS)
#define WT_FLOATS  (128 * 512)               // WT[k][c] = qk_w[c][k]

// ---------------------------------------------------------------------------
// Prep: transpose qk_w (512x128) -> WT (128x512).
// ---------------------------------------------------------------------------
__global__ void wt_kernel(const float* __restrict__ qk_w, float* __restrict__ WT) {
  const int k = blockIdx.x;
  const int t = threadIdx.x;
#pragma unroll
  for (int i = 0; i < 2; ++i) {
    const int c = t + 256 * i;
    WT[k * 512 + c] = qk_w[(size_t)c * 128 + k];
  }
}

// ---------------------------------------------------------------------------
// Kernel A: per (b, head, half): conv K (32 ch x 1568 pos, 7 tiles of 256),
// kv[32][32] accumulated in registers, cross-wave reduce aliased onto KT.
// 512 threads (8 waves), 2 blocks/CU. Flat grid 512 with XCD grouping:
// all 8 head-blocks of one (s,b) share bid%8 -> same XCD L2 for conv input.
// ---------------------------------------------------------------------------
__global__ __launch_bounds__(512, 4)
void kv_kernel(const float* __restrict__ x, const float* __restrict__ WT,
               const float* __restrict__ qk_b, float* __restrict__ kv2,
               float* __restrict__ km2) {
  const int bid = blockIdx.x;
  const int h = bid >> 6;          // 0..7
  const int g = bid & 63;          // (s,b) group; bid%8 == g%8 for all h
  const int s = g & 1;
  const int b = g >> 1;
  const int t = threadIdx.x;       // 0..511
  const int chg = t >> 6;          // 0..7 (4 channels each) == wave index
  const int pg  = t & 63;          // f4-position within 256-pos tile
  const int wave = t >> 6, lane = t & 63;
  const int dg = lane >> 3, eg = lane & 7;

  __shared__ float KT[256][36];    // [pos][ch-local], +4 pad; reused for reduce
  __shared__ float VT[256][36];
  __shared__ float kmred[32];

  float kvacc[4][4] = {};
  float kmacc[4] = {0.f, 0.f, 0.f, 0.f};

  const float* wk = WT + 256 + h * HD + chg * 4;                      // +k*512
  const float* xk = x + ((size_t)(b * NCH + 128)) * NPIX + s * 1568;  // conv in
  const float* xv = x + ((size_t)(b * NCH + h * HD)) * NPIX + s * 1568;  // V
  const float4 b4 = *(const float4*)(qk_b + 256 + h * HD + chg * 4);
  const float br[4] = {b4.x, b4.y, b4.z, b4.w};

  for (int tile = 0; tile < 7; ++tile) {
    const int p0 = tile * 256;
    const int L = (tile == 6) ? 32 : 256;
    const bool act = (pg * 4 < L);

    // ---- conv: 4ch x 4pos register tile, direct-global reads ----
    float a[4][4] = {};
    if (act) {
      const float* xp = xk + p0 + pg * 4;
#pragma unroll 4
      for (int k = 0; k < 128; ++k) {
        const float4 w4 = *(const float4*)(wk + k * 512);
        const float4 x4 = *(const float4*)(xp + (size_t)k * NPIX);
        const float wr[4] = {w4.x, w4.y, w4.z, w4.w};
        const float xr[4] = {x4.x, x4.y, x4.z, x4.w};
#pragma unroll
        for (int ci = 0; ci < 4; ++ci)
#pragma unroll
          for (int pi = 0; pi < 4; ++pi) a[ci][pi] += wr[ci] * xr[pi];
      }
    }

    __syncthreads();  // previous tile's LDS fully consumed

    // ---- bias + elu+1, km partial, stage K^T ----
    if (act) {
#pragma unroll
      for (int pi = 0; pi < 4; ++pi) {
        float kv4[4];
#pragma unroll
        for (int ci = 0; ci < 4; ++ci) {
          float v = a[ci][pi] + br[ci];
          v = (v > 0.f) ? (v + 1.f) : __expf(v);
          kmacc[ci] += v;
          kv4[ci] = v;
        }
        *(float4*)&KT[pg * 4 + pi][chg * 4] =
            make_float4(kv4[0], kv4[1], kv4[2], kv4[3]);
      }
    }
    // ---- stage V^T: 32 ch x 64 f4-pos = 2048 f4 / 512 thr ----
#pragma unroll
    for (int rr = 0; rr < 4; ++rr) {
      const int id = t + 512 * rr;     // 0..2047
      const int cc = id >> 6;          // 0..31
      const int pf = id & 63;
      if (pf * 4 < L) {
        const float4 v = *(const float4*)(xv + (size_t)cc * NPIX + p0 + pf * 4);
        VT[pf * 4 + 0][cc] = v.x;
        VT[pf * 4 + 1][cc] = v.y;
        VT[pf * 4 + 2][cc] = v.z;
        VT[pf * 4 + 3][cc] = v.w;
      }
    }
    __syncthreads();

    // ---- kv accumulate: wave w owns positions [w*32, w*32+32) ----
    const int pend = min(wave * 32 + 32, L);
    for (int p = wave * 32; p < pend; ++p) {
      const float4 kf = *(const float4*)&KT[p][dg * 4];
      const float4 vf = *(const float4*)&VT[p][eg * 4];
      const float kr[4] = {kf.x, kf.y, kf.z, kf.w};
      const float vr[4] = {vf.x, vf.y, vf.z, vf.w};
#pragma unroll
      for (int di = 0; di < 4; ++di)
#pragma unroll
        for (int ei = 0; ei < 4; ++ei) kvacc[di][ei] += kr[di] * vr[ei];
    }
  }

  // ---- cross-wave reduce: scratch aliased onto KT (8x1024 <= 9216 floats) --
  __syncthreads();
  if (t < 32) kmred[t] = 0.f;
  float* redp = &KT[0][0];
#pragma unroll
  for (int di = 0; di < 4; ++di)
#pragma unroll
    for (int ei = 0; ei < 4; ++ei)
      redp[wave * 1024 + (dg * 4 + di) * 32 + eg * 4 + ei] = kvacc[di][ei];
  __syncthreads();

  float* kvdst = kv2 + (((size_t)s * NB + b) * NH + h) * 1024;
#pragma unroll
  for (int i = 0; i < 2; ++i) {
    const int e = t + 512 * i;
    float ssum = 0.f;
#pragma unroll
    for (int w = 0; w < 8; ++w) ssum += redp[w * 1024 + e];
    kvdst[e] = ssum;
  }
#pragma unroll
  for (int ci = 0; ci < 4; ++ci) atomicAdd(&kmred[chg * 4 + ci], kmacc[ci]);
  __syncthreads();
  if (t < 32) km2[(((size_t)s * NB + b) * NH + h) * HD + t] = kmred[t];
}

// ---------------------------------------------------------------------------
// Kernel B: Q = elu(Wq @ x0)+1, out = (Q^T kv')/(Q^T km' + eps).
// 2-head groups (4 iterations) -> LDS ~26 KB -> 6 blocks/CU.
// Grid (49, 32), 256 threads.
// ---------------------------------------------------------------------------
__global__ __launch_bounds__(256)
void out_kernel(const float* __restrict__ x, const float* __restrict__ WT,
                const float* __restrict__ qk_b, const float* __restrict__ kv2,
                const float* __restrict__ km2, float* __restrict__ out) {
  const int b = blockIdx.y;
  const int p0 = blockIdx.x * 64;
  const int t = threadIdx.x;
  const int chg = t >> 3, pg = t & 7;
  const int c0 = chg * 8, pq0 = pg * 8;

  __shared__ float QT[64 * 68];       // [ch-local 0..63][pos], stride 68
  __shared__ float kvs[2][32][32];    // current 2 heads, pre-scaled
  __shared__ float kms[64];

  // ---- conv GEMM for Q: 8ch x 8pos register tile (all 256 q-channels) ----
  float acc[8][8];
#pragma unroll
  for (int i = 0; i < 8; ++i)
#pragma unroll
    for (int j = 0; j < 8; ++j) acc[i][j] = 0.f;

  const float* xk = x + ((size_t)b * NCH) * NPIX + p0 + pq0;
  const float* wk = WT + c0;
#pragma unroll 4
  for (int k = 0; k < 128; ++k) {
    const float4 wa = *(const float4*)(wk + k * 512);
    const float4 wb = *(const float4*)(wk + k * 512 + 4);
    const float4 xa = *(const float4*)(xk + (size_t)k * NPIX);
    const float4 xb = *(const float4*)(xk + (size_t)k * NPIX + 4);
    const float wr[8] = {wa.x, wa.y, wa.z, wa.w, wb.x, wb.y, wb.z, wb.w};
    const float xr[8] = {xa.x, xa.y, xa.z, xa.w, xb.x, xb.y, xb.z, xb.w};
#pragma unroll
    for (int ci = 0; ci < 8; ++ci)
#pragma unroll
      for (int pi = 0; pi < 8; ++pi) acc[ci][pi] += wr[ci] * xr[pi];
  }
  {
    const float4 ba = *(const float4*)(qk_b + c0);
    const float4 bb = *(const float4*)(qk_b + c0 + 4);
    const float br[8] = {ba.x, ba.y, ba.z, ba.w, bb.x, bb.y, bb.z, bb.w};
#pragma unroll
    for (int ci = 0; ci < 8; ++ci)
#pragma unroll
      for (int pi = 0; pi < 8; ++pi) {
        float v = acc[ci][pi] + br[ci];
        acc[ci][pi] = (v > 0.f) ? (v + 1.f) : __expf(v);
      }
  }

  // num-phase thread mapping: (local head, 4-wide e group, 4 consecutive pos)
  const int h_l = t >> 7;          // 0..1
  const int eg  = (t >> 4) & 7;    // e = eg*4 .. +4
  const int pg2 = t & 15;          // positions pg2*4 .. +4

  for (int g2 = 0; g2 < 4; ++g2) {
    __syncthreads();  // prev group's num phase done with QT/kvs
    // stage kv' (sum of halves) and km' for heads g2*2, g2*2+1
    {
      const float4* s0 = (const float4*)(kv2 + ((size_t)(0 * NB + b) * NH + g2 * 2) * 1024);
      const float4* s1 = (const float4*)(kv2 + ((size_t)(1 * NB + b) * NH + g2 * 2) * 1024);
      float4* dst = (float4*)kvs;
#pragma unroll
      for (int r = 0; r < 2; ++r) {
        const int id = t + 256 * r;
        const float4 u = s0[id];
        const float4 w = s1[id];
        dst[id] = make_float4((u.x + w.x) * INV_N, (u.y + w.y) * INV_N,
                              (u.z + w.z) * INV_N, (u.w + w.w) * INV_N);
      }
      if (t < 64) {
        const int hh = g2 * 2 + (t >> 5), cc = t & 31;
        kms[t] = (km2[((size_t)(0 * NB + b) * NH + hh) * HD + cc] +
                  km2[((size_t)(1 * NB + b) * NH + hh) * HD + cc]) * INV_N;
      }
    }
    // stage Q for this group's 64 channels: [ch][pos] layout, f4 rows
    if ((chg >> 3) == g2) {
      const int cl0 = (chg & 7) * 8;
#pragma unroll
      for (int ci = 0; ci < 8; ++ci) {
        *(float4*)(QT + (cl0 + ci) * 68 + pq0) =
            make_float4(acc[ci][0], acc[ci][1], acc[ci][2], acc[ci][3]);
        *(float4*)(QT + (cl0 + ci) * 68 + pq0 + 4) =
            make_float4(acc[ci][4], acc[ci][5], acc[ci][6], acc[ci][7]);
      }
    }
    __syncthreads();

    // num/den over 32 d; thread covers 4 e x 4 consecutive positions
    float nacc[4][4] = {};
    float den[4] = {0.f, 0.f, 0.f, 0.f};
#pragma unroll 2
    for (int dq = 0; dq < 8; ++dq) {
      float4 kvv[4];
#pragma unroll
      for (int di = 0; di < 4; ++di)
        kvv[di] = *(const float4*)&kvs[h_l][dq * 4 + di][eg * 4];
      const float4 kmv = *(const float4*)&kms[h_l * 32 + dq * 4];
      const float kmr[4] = {kmv.x, kmv.y, kmv.z, kmv.w};
#pragma unroll
      for (int di = 0; di < 4; ++di) {
        const float4 q4 =
            *(const float4*)(QT + (h_l * 32 + dq * 4 + di) * 68 + pg2 * 4);
        const float qr[4] = {q4.x, q4.y, q4.z, q4.w};
#pragma unroll
        for (int j = 0; j < 4; ++j) {
          den[j] += qr[j] * kmr[di];
          nacc[0][j] += qr[j] * kvv[di].x;
          nacc[1][j] += qr[j] * kvv[di].y;
          nacc[2][j] += qr[j] * kvv[di].z;
          nacc[3][j] += qr[j] * kvv[di].w;
        }
      }
    }
    float rden[4];
#pragma unroll
    for (int j = 0; j < 4; ++j) rden[j] = 1.0f / (den[j] + 1e-6f);

    // f4 stores: channel c, positions p0 + pg2*4 .. +4
#pragma unroll
    for (int ei = 0; ei < 4; ++ei) {
      const int c = g2 * 64 + h_l * 32 + eg * 4 + ei;
      float* oc = out + ((size_t)(b * NCH + c)) * NPIX + p0 + pg2 * 4;
      *(float4*)oc = make_float4(nacc[ei][0] * rden[0], nacc[ei][1] * rden[1],
                                 nacc[ei][2] * rden[2], nacc[ei][3] * rden[3]);
    }
  }
}

// ---------------------------------------------------------------------------
// Kernel C: depthwise 3x3 pe conv, added into out (RMW). One thread per
// (channel, row), sliding float4 window along the row.
// ---------------------------------------------------------------------------
__global__ __launch_bounds__(256)
void pe_kernel(const float* __restrict__ x, const float* __restrict__ pe_w,
               const float* __restrict__ pe_b, float* __restrict__ out) {
  const int b = blockIdx.y;
  const int c = blockIdx.x * 4 + (threadIdx.x >> 6);
  const int r = threadIdx.x & 63;
  if (r >= 56) return;

  const float* xc = x + ((size_t)(b * NCH + c)) * NPIX;
  float* oc = out + ((size_t)(b * NCH + c)) * NPIX + r * 56;

  float pw[9];
#pragma unroll
  for (int i = 0; i < 9; ++i) pw[i] = pe_w[c * 9 + i];
  const float pb = pe_b[c];

  const bool hasU = (r > 0), hasD = (r < 55);
  const float* rowU = xc + (r - 1) * 56;
  const float* row0 = xc + r * 56;
  const float* rowD = xc + (r + 1) * 56;
  const float4 Z = {0.f, 0.f, 0.f, 0.f};

  float4 um[4], u0[4], ud[4];
  um[0] = Z; u0[0] = Z; ud[0] = Z;
#pragma unroll
  for (int k = 1; k < 4; ++k) {
    const int col = (k - 1) * 4;
    um[k] = hasU ? *(const float4*)(rowU + col) : Z;
    u0[k] = *(const float4*)(row0 + col);
    ud[k] = hasD ? *(const float4*)(rowD + col) : Z;
  }

  for (int jc = 0; jc < 7; ++jc) {
    const int p0 = jc * 8;
    float wm[16], w0[16], wd[16];
#pragma unroll
    for (int k = 0; k < 4; ++k) {
      wm[4 * k] = um[k].x; wm[4 * k + 1] = um[k].y; wm[4 * k + 2] = um[k].z; wm[4 * k + 3] = um[k].w;
      w0[4 * k] = u0[k].x; w0[4 * k + 1] = u0[k].y; w0[4 * k + 2] = u0[k].z; w0[4 * k + 3] = u0[k].w;
      wd[4 * k] = ud[k].x; wd[4 * k + 1] = ud[k].y; wd[4 * k + 2] = ud[k].z; wd[4 * k + 3] = ud[k].w;
    }
    float res[8];
#pragma unroll
    for (int p = 0; p < 8; ++p) {
      float s = pb;
      s += pw[0] * wm[3 + p] + pw[1] * wm[4 + p] + pw[2] * wm[5 + p];
      s += pw[3] * w0[3 + p] + pw[4] * w0[4 + p] + pw[5] * w0[5 + p];
      s += pw[6] * wd[3 + p] + pw[7] * wd[4 + p] + pw[8] * wd[5 + p];
      res[p] = s;
    }
    float4 o0 = *(const float4*)(oc + p0);
    float4 o1 = *(const float4*)(oc + p0 + 4);
    o0.x += res[0]; o0.y += res[1]; o0.z += res[2]; o0.w += res[3];
    o1.x += res[4]; o1.y += res[5]; o1.z += res[6]; o1.w += res[7];
    *(float4*)(oc + p0) = o0;
    *(float4*)(oc + p0 + 4) = o1;

    if (jc < 6) {
      um[0] = um[2]; um[1] = um[3];
      u0[0] = u0[2]; u0[1] = u0[3];
      ud[0] = ud[2]; ud[1] = ud[3];
      const int cA = p0 + 12, cB = p0 + 16;
      const bool okB = (cB < 56);
      um[2] = hasU ? *(const float4*)(rowU + cA) : Z;
      u0[2] = *(const float4*)(row0 + cA);
      ud[2] = hasD ? *(const float4*)(rowD + cA) : Z;
      um[3] = (hasU && okB) ? *(const float4*)(rowU + cB) : Z;
      u0[3] = okB ? *(const float4*)(row0 + cB) : Z;
      ud[3] = (hasD && okB) ? *(const float4*)(rowD + cB) : Z;
    }
  }
}

extern "C" void kernel_launch(void* const* d_in, const int* in_sizes, int n_in,
                              void* d_out, int out_size, void* d_ws,
                              size_t ws_size, hipStream_t stream) {
  const float* x    = (const float*)d_in[0];
  const float* qk_w = (const float*)d_in[1];
  const float* qk_b = (const float*)d_in[2];
  const float* pe_w = (const float*)d_in[3];
  const float* pe_b = (const float*)d_in[4];
  float* out = (float*)d_out;
  float* kv2 = (float*)d_ws;
  float* km2 = kv2 + KV2_FLOATS;
  float* WT  = kv2 + WT_OFFSET;

  wt_kernel<<<128, 256, 0, stream>>>(qk_w, WT);

  kv_kernel<<<512, 512, 0, stream>>>(x, WT, qk_b, kv2, km2);

  dim3 g2(49, NB);
  out_kernel<<<g2, 256, 0, stream>>>(x, WT, qk_b, kv2, km2, out);

  dim3 g3(64, NB);
  pe_kernel<<<g3, 256, 0, stream>>>(x, pe_w, pe_b, out);
}

// Round 5
// 310.966 us; speedup vs baseline: 5.3961x; 1.8116x over previous
//
#include <hip/hip_runtime.h>
#include <cmath>

#define NCH   256
#define NPIX  3136
#define NB    32
#define SEV   7
#define INV_N (1.0f / 3136.0f)

typedef __attribute__((ext_vector_type(8)))  short bf16x8;
typedef __attribute__((ext_vector_type(4)))  float f32x4;
typedef __attribute__((ext_vector_type(16))) float f32x16;

// ws layout (float offsets)
#define KV7_F  (SEV * NB * 8 * 1024)   // 1,835,008
#define KM7_F  (SEV * NB * 256)        // 57,344
#define KVF_F  (NB * 8 * 1024)         // 262,144
#define KMF_F  (NB * 256)              // 8,192
#define KM7_OFF (KV7_F)
#define KVF_OFF (KM7_OFF + KM7_F)
#define KMF_OFF (KVF_OFF + KVF_F)
#define WF_OFF  (KMF_OFF + KMF_F)      // ushort region (16B aligned: offset*4 % 16 == 0)

__device__ __forceinline__ ushort f2bf(float f) {
  unsigned u = __float_as_uint(f);
  u += 0x7FFFu + ((u >> 16) & 1u);
  return (ushort)(u >> 16);
}
__device__ __forceinline__ float bf2f(ushort h) {
  return __uint_as_float(((unsigned)h) << 16);
}

// ---------------------------------------------------------------------------
// Prep: qk_w (512x128) -> MFMA A-fragment layout, bf16 hi/lo split.
// element (side, hl, mt, ks, lane, j): ch = mt*16+(lane&15), k = ks*32+(lane>>4)*8+j
// ---------------------------------------------------------------------------
__global__ void wfrag_kernel(const float* __restrict__ qk_w, ushort* __restrict__ Wf) {
  const int tid = blockIdx.x * 512 + threadIdx.x;   // 0..16383
  const int lane = tid & 63;
  const int ks = (tid >> 6) & 3;
  const int mt = (tid >> 8) & 15;
  const int hl = (tid >> 12) & 1;
  const int side = (tid >> 13) & 1;
  const int ch = mt * 16 + (lane & 15);
  const int oc = side * 256 + ch;
  ushort v[8];
#pragma unroll
  for (int j = 0; j < 8; ++j) {
    const int k = ks * 32 + (lane >> 4) * 8 + j;
    const float w = qk_w[(size_t)oc * 128 + k];
    const ushort hi = f2bf(w);
    v[j] = (hl == 0) ? hi : f2bf(w - bf2f(hi));
  }
  *(uint4*)(Wf + (size_t)tid * 8) = *(const uint4*)v;
}

// ---------------------------------------------------------------------------
// Kernel A: K-conv via MFMA (W hi/lo split), K staged bf16 in LDS, kv einsum
// via 32x32x16 MFMA (A=K from LDS, B=V direct from global w/ cvt).
// Grid 224: bid -> b = bid&31 (XCD-group by b), sev = bid>>5. 512 thr.
// ---------------------------------------------------------------------------
__global__ __launch_bounds__(512, 2)
void kv_kernel(const float* __restrict__ x, const ushort* __restrict__ Wf,
               const float* __restrict__ qk_b, float* __restrict__ kv7,
               float* __restrict__ km7) {
  const int bid = blockIdx.x;
  const int b = bid & 31, sev = bid >> 5;
  const int t = threadIdx.x;
  const int wave = t >> 6, l = t & 63;
  const int q = l >> 4, r15 = l & 15;
  const int e = l & 31, q5 = l >> 5;
  const int mw = wave & 3, ng = wave >> 2;  // conv: 4 M-waves x 2 N-groups
  const int h = wave;                        // einsum: wave = head

  __shared__ ushort Xb[64][136];   // [pos][in-ch k] bf16, 17.4 KB
  __shared__ ushort Kst[256][80];  // [k-ch][pos] bf16, 41 KB
  __shared__ float kmred[256];

  // resident W A-frags (side 1 = k-conv): 4 Mtiles x 4 ksteps x hi/lo
  bf16x8 wf[4][4][2];
#pragma unroll
  for (int mti = 0; mti < 4; ++mti)
#pragma unroll
    for (int ks = 0; ks < 4; ++ks)
#pragma unroll
      for (int hl = 0; hl < 2; ++hl) {
        const size_t off =
            (size_t)(((((2 + hl) * 16 + (mw * 4 + mti)) * 4 + ks) * 64 + l)) * 8;
        wf[mti][ks][hl] = *(const bf16x8*)(Wf + off);
      }

  float bias[4][4];
#pragma unroll
  for (int mti = 0; mti < 4; ++mti)
#pragma unroll
    for (int r = 0; r < 4; ++r)
      bias[mti][r] = qk_b[256 + (mw * 4 + mti) * 16 + q * 4 + r];

  f32x16 kvacc;
#pragma unroll
  for (int i = 0; i < 16; ++i) kvacc[i] = 0.f;
  if (t < 256) kmred[t] = 0.f;

  const float* xk = x + ((size_t)(b * NCH) + 128) * NPIX + sev * 448;
  const float* xv = x + ((size_t)(b * NCH) + h * 32 + e) * NPIX + sev * 448;

  for (int st = 0; st < SEV; ++st) {
    const int pos0 = st * 64;
    // ---- stage X (transpose to [pos][k], bf16) ----
#pragma unroll
    for (int rr = 0; rr < 4; ++rr) {
      const int id = t + 512 * rr;     // 0..2047
      const int ch = id >> 4;          // 0..127
      const int p4 = (id & 15) * 4;
      const float4 v = *(const float4*)(xk + (size_t)ch * NPIX + pos0 + p4);
      Xb[p4 + 0][ch] = f2bf(v.x);
      Xb[p4 + 1][ch] = f2bf(v.y);
      Xb[p4 + 2][ch] = f2bf(v.z);
      Xb[p4 + 3][ch] = f2bf(v.w);
    }
    __syncthreads();

    // ---- conv MFMA: wave covers Mtiles mw*4..+4, Ntiles ng*2..+2 ----
    f32x4 acc[4][2];
#pragma unroll
    for (int i = 0; i < 4; ++i)
#pragma unroll
      for (int nt = 0; nt < 2; ++nt)
#pragma unroll
        for (int r = 0; r < 4; ++r) acc[i][nt][r] = 0.f;
#pragma unroll
    for (int ks = 0; ks < 4; ++ks) {
      const bf16x8 xb0 = *(const bf16x8*)&Xb[(ng * 2 + 0) * 16 + r15][ks * 32 + q * 8];
      const bf16x8 xb1 = *(const bf16x8*)&Xb[(ng * 2 + 1) * 16 + r15][ks * 32 + q * 8];
#pragma unroll
      for (int mti = 0; mti < 4; ++mti) {
        acc[mti][0] = __builtin_amdgcn_mfma_f32_16x16x32_bf16(wf[mti][ks][0], xb0, acc[mti][0], 0, 0, 0);
        acc[mti][0] = __builtin_amdgcn_mfma_f32_16x16x32_bf16(wf[mti][ks][1], xb0, acc[mti][0], 0, 0, 0);
        acc[mti][1] = __builtin_amdgcn_mfma_f32_16x16x32_bf16(wf[mti][ks][0], xb1, acc[mti][1], 0, 0, 0);
        acc[mti][1] = __builtin_amdgcn_mfma_f32_16x16x32_bf16(wf[mti][ks][1], xb1, acc[mti][1], 0, 0, 0);
      }
    }

    // ---- epilogue: bias + elu+1, stage K bf16 [ch][pos], km reduce ----
#pragma unroll
    for (int mti = 0; mti < 4; ++mti) {
      float kmr[4] = {0.f, 0.f, 0.f, 0.f};
#pragma unroll
      for (int nt = 0; nt < 2; ++nt) {
        const int pos = (ng * 2 + nt) * 16 + r15;
#pragma unroll
        for (int r = 0; r < 4; ++r) {
          float v = acc[mti][nt][r] + bias[mti][r];
          v = (v > 0.f) ? (v + 1.f) : __expf(v);
          kmr[r] += v;
          Kst[(mw * 4 + mti) * 16 + q * 4 + r][pos] = f2bf(v);
        }
      }
#pragma unroll
      for (int r = 0; r < 4; ++r) {
        float s = kmr[r];
        s += __shfl_xor(s, 1);
        s += __shfl_xor(s, 2);
        s += __shfl_xor(s, 4);
        s += __shfl_xor(s, 8);
        if (r15 == 0)
          atomicAdd(&kmred[(mw * 4 + mti) * 16 + q * 4 + r], s);
      }
    }
    __syncthreads();

    // ---- kv einsum: per head-wave, 4 x mfma_32x32x16 over 64 pos ----
#pragma unroll
    for (int ks = 0; ks < 4; ++ks) {
      const bf16x8 ak = *(const bf16x8*)&Kst[h * 32 + e][ks * 16 + q5 * 8];
      const float* vp = xv + pos0 + ks * 16 + q5 * 8;
      const float4 v0 = *(const float4*)vp;
      const float4 v1 = *(const float4*)(vp + 4);
      bf16x8 bv;
      bv[0] = (short)f2bf(v0.x); bv[1] = (short)f2bf(v0.y);
      bv[2] = (short)f2bf(v0.z); bv[3] = (short)f2bf(v0.w);
      bv[4] = (short)f2bf(v1.x); bv[5] = (short)f2bf(v1.y);
      bv[6] = (short)f2bf(v1.z); bv[7] = (short)f2bf(v1.w);
      kvacc = __builtin_amdgcn_mfma_f32_32x32x16_bf16(ak, bv, kvacc, 0, 0, 0);
    }
  }

  // ---- write partials: 32x32 C-layout col=l&31, row=(reg&3)+8(reg>>2)+4q5 ----
  float* dst = kv7 + ((size_t)(sev * NB + b) * 8 + h) * 1024;
#pragma unroll
  for (int reg = 0; reg < 16; ++reg) {
    const int row = (reg & 3) + 8 * (reg >> 2) + 4 * q5;
    dst[row * 32 + e] = kvacc[reg];
  }
  __syncthreads();
  if (t < 256) km7[(size_t)(sev * NB + b) * 256 + t] = kmred[t];
}

// ---------------------------------------------------------------------------
// Reduce: sum 7 partials, scale by 1/n.
// ---------------------------------------------------------------------------
__global__ void red_kernel(const float* __restrict__ kv7, const float* __restrict__ km7,
                           float* __restrict__ kvF, float* __restrict__ kmF) {
  const int b = blockIdx.x;
  const int t = threadIdx.x;
  for (int i = t; i < 8192; i += 256) {
    float s = 0.f;
#pragma unroll
    for (int sv = 0; sv < SEV; ++sv)
      s += kv7[(size_t)(sv * NB + b) * 8192 + i];
    kvF[(size_t)b * 8192 + i] = s * INV_N;
  }
  {
    float s = 0.f;
#pragma unroll
    for (int sv = 0; sv < SEV; ++sv)
      s += km7[(size_t)(sv * NB + b) * 256 + t];
    kmF[b * 256 + t] = s * INV_N;
  }
}

// ---------------------------------------------------------------------------
// Kernel B: Q-conv via MFMA, Q staged bf16 [pos][ch] (b64-packed), den in f32
// VALU from conv regs, num via 16x16x32 MFMA (A=Q^T, B=kv'), f4 out stores.
// ---------------------------------------------------------------------------
__global__ __launch_bounds__(512, 2)
void out_kernel(const float* __restrict__ x, const ushort* __restrict__ Wf,
                const float* __restrict__ qk_b, const float* __restrict__ kvF,
                const float* __restrict__ kmF, float* __restrict__ out) {
  const int bid = blockIdx.x;
  const int b = bid & 31, sev = bid >> 5;
  const int t = threadIdx.x;
  const int wave = t >> 6, l = t & 63;
  const int q = l >> 4, r15 = l & 15;
  const int mw = wave & 3, ng = wave >> 2;
  const int h = wave;

  __shared__ ushort Xb[64][136];
  __shared__ ushort QT[64][264];   // [pos][q-ch] bf16
  __shared__ float denT[8][64];

  // resident W A-frags (side 0 = q-conv)
  bf16x8 wf[4][4][2];
#pragma unroll
  for (int mti = 0; mti < 4; ++mti)
#pragma unroll
    for (int ks = 0; ks < 4; ++ks)
#pragma unroll
      for (int hl = 0; hl < 2; ++hl) {
        const size_t off =
            (size_t)((((hl * 16 + (mw * 4 + mti)) * 4 + ks) * 64 + l)) * 8;
        wf[mti][ks][hl] = *(const bf16x8*)(Wf + off);
      }

  float bias[4][4], kmw[4][4];
#pragma unroll
  for (int mti = 0; mti < 4; ++mti)
#pragma unroll
    for (int r = 0; r < 4; ++r) {
      const int c = (mw * 4 + mti) * 16 + q * 4 + r;
      bias[mti][r] = qk_b[c];
      kmw[mti][r] = kmF[b * 256 + c];
    }

  // kv' B-frags per head: col = l&15 (e within half), k = d = q*8+j
  bf16x8 bkv[2];
#pragma unroll
  for (int eh = 0; eh < 2; ++eh) {
#pragma unroll
    for (int j = 0; j < 8; ++j)
      bkv[eh][j] = (short)f2bf(
          kvF[(size_t)b * 8192 + h * 1024 + (q * 8 + j) * 32 + eh * 16 + r15]);
  }

  const float* xq = x + (size_t)(b * NCH) * NPIX + sev * 448;

  for (int st = 0; st < SEV; ++st) {
    const int pos0 = st * 64;
#pragma unroll
    for (int rr = 0; rr < 4; ++rr) {
      const int id = t + 512 * rr;
      const int ch = id >> 4;
      const int p4 = (id & 15) * 4;
      const float4 v = *(const float4*)(xq + (size_t)ch * NPIX + pos0 + p4);
      Xb[p4 + 0][ch] = f2bf(v.x);
      Xb[p4 + 1][ch] = f2bf(v.y);
      Xb[p4 + 2][ch] = f2bf(v.z);
      Xb[p4 + 3][ch] = f2bf(v.w);
    }
    __syncthreads();

    f32x4 acc[4][2];
#pragma unroll
    for (int i = 0; i < 4; ++i)
#pragma unroll
      for (int nt = 0; nt < 2; ++nt)
#pragma unroll
        for (int r = 0; r < 4; ++r) acc[i][nt][r] = 0.f;
#pragma unroll
    for (int ks = 0; ks < 4; ++ks) {
      const bf16x8 xb0 = *(const bf16x8*)&Xb[(ng * 2 + 0) * 16 + r15][ks * 32 + q * 8];
      const bf16x8 xb1 = *(const bf16x8*)&Xb[(ng * 2 + 1) * 16 + r15][ks * 32 + q * 8];
#pragma unroll
      for (int mti = 0; mti < 4; ++mti) {
        acc[mti][0] = __builtin_amdgcn_mfma_f32_16x16x32_bf16(wf[mti][ks][0], xb0, acc[mti][0], 0, 0, 0);
        acc[mti][0] = __builtin_amdgcn_mfma_f32_16x16x32_bf16(wf[mti][ks][1], xb0, acc[mti][0], 0, 0, 0);
        acc[mti][1] = __builtin_amdgcn_mfma_f32_16x16x32_bf16(wf[mti][ks][0], xb1, acc[mti][1], 0, 0, 0);
        acc[mti][1] = __builtin_amdgcn_mfma_f32_16x16x32_bf16(wf[mti][ks][1], xb1, acc[mti][1], 0, 0, 0);
      }
    }

    // epilogue: elu+1 -> QT (b64-packed), den partials (f32, exact Q)
    float pdh[2][2];
    pdh[0][0] = pdh[0][1] = pdh[1][0] = pdh[1][1] = 0.f;
#pragma unroll
    for (int mti = 0; mti < 4; ++mti) {
#pragma unroll
      for (int nt = 0; nt < 2; ++nt) {
        ushort pk[4];
        float dsum = 0.f;
#pragma unroll
        for (int r = 0; r < 4; ++r) {
          float v = acc[mti][nt][r] + bias[mti][r];
          v = (v > 0.f) ? (v + 1.f) : __expf(v);
          pk[r] = f2bf(v);
          dsum += v * kmw[mti][r];
        }
        *(uint2*)&QT[(ng * 2 + nt) * 16 + r15][(mw * 4 + mti) * 16 + q * 4] =
            *(const uint2*)pk;
        pdh[mti >> 1][nt] += dsum;
      }
    }
#pragma unroll
    for (int ht = 0; ht < 2; ++ht)
#pragma unroll
      for (int nt = 0; nt < 2; ++nt) {
        float s = pdh[ht][nt];
        s += __shfl_xor(s, 16);
        s += __shfl_xor(s, 32);
        if (q == 0) denT[mw * 2 + ht][(ng * 2 + nt) * 16 + r15] = s;
      }
    __syncthreads();

    // num MFMA + divide + f4 stores
#pragma unroll
    for (int pt = 0; pt < 4; ++pt) {
      const bf16x8 aq = *(const bf16x8*)&QT[pt * 16 + r15][h * 32 + q * 8];
      f32x4 z;
      z[0] = z[1] = z[2] = z[3] = 0.f;
      const f32x4 n0 = __builtin_amdgcn_mfma_f32_16x16x32_bf16(aq, bkv[0], z, 0, 0, 0);
      const f32x4 n1 = __builtin_amdgcn_mfma_f32_16x16x32_bf16(aq, bkv[1], z, 0, 0, 0);
      float4 o0, o1;
      float rdn[4];
#pragma unroll
      for (int r = 0; r < 4; ++r)
        rdn[r] = 1.0f / (denT[h][pt * 16 + q * 4 + r] + 1e-6f);
      o0.x = n0[0] * rdn[0]; o0.y = n0[1] * rdn[1];
      o0.z = n0[2] * rdn[2]; o0.w = n0[3] * rdn[3];
      o1.x = n1[0] * rdn[0]; o1.y = n1[1] * rdn[1];
      o1.z = n1[2] * rdn[2]; o1.w = n1[3] * rdn[3];
      const int posg = sev * 448 + pos0 + pt * 16 + q * 4;
      const int c0 = h * 32 + r15;
      const int c1 = h * 32 + 16 + r15;
      *(float4*)(out + ((size_t)(b * NCH + c0)) * NPIX + posg) = o0;
      *(float4*)(out + ((size_t)(b * NCH + c1)) * NPIX + posg) = o1;
    }
  }
}

// ---------------------------------------------------------------------------
// Kernel C: depthwise 3x3 pe conv, added into out (RMW), sliding f4 window.
// ---------------------------------------------------------------------------
__global__ __launch_bounds__(256)
void pe_kernel(const float* __restrict__ x, const float* __restrict__ pe_w,
               const float* __restrict__ pe_b, float* __restrict__ out) {
  const int b = blockIdx.y;
  const int c = blockIdx.x * 4 + (threadIdx.x >> 6);
  const int r = threadIdx.x & 63;
  if (r >= 56) return;

  const float* xc = x + ((size_t)(b * NCH + c)) * NPIX;
  float* oc = out + ((size_t)(b * NCH + c)) * NPIX + r * 56;

  float pw[9];
#pragma unroll
  for (int i = 0; i < 9; ++i) pw[i] = pe_w[c * 9 + i];
  const float pb = pe_b[c];

  const bool hasU = (r > 0), hasD = (r < 55);
  const float* rowU = xc + (r - 1) * 56;
  const float* row0 = xc + r * 56;
  const float* rowD = xc + (r + 1) * 56;
  const float4 Z = {0.f, 0.f, 0.f, 0.f};

  float4 um[4], u0[4], ud[4];
  um[0] = Z; u0[0] = Z; ud[0] = Z;
#pragma unroll
  for (int k = 1; k < 4; ++k) {
    const int col = (k - 1) * 4;
    um[k] = hasU ? *(const float4*)(rowU + col) : Z;
    u0[k] = *(const float4*)(row0 + col);
    ud[k] = hasD ? *(const float4*)(rowD + col) : Z;
  }

  for (int jc = 0; jc < 7; ++jc) {
    const int p0 = jc * 8;
    float wm[16], w0[16], wd[16];
#pragma unroll
    for (int k = 0; k < 4; ++k) {
      wm[4 * k] = um[k].x; wm[4 * k + 1] = um[k].y; wm[4 * k + 2] = um[k].z; wm[4 * k + 3] = um[k].w;
      w0[4 * k] = u0[k].x; w0[4 * k + 1] = u0[k].y; w0[4 * k + 2] = u0[k].z; w0[4 * k + 3] = u0[k].w;
      wd[4 * k] = ud[k].x; wd[4 * k + 1] = ud[k].y; wd[4 * k + 2] = ud[k].z; wd[4 * k + 3] = ud[k].w;
    }
    float res[8];
#pragma unroll
    for (int p = 0; p < 8; ++p) {
      float s = pb;
      s += pw[0] * wm[3 + p] + pw[1] * wm[4 + p] + pw[2] * wm[5 + p];
      s += pw[3] * w0[3 + p] + pw[4] * w0[4 + p] + pw[5] * w0[5 + p];
      s += pw[6] * wd[3 + p] + pw[7] * wd[4 + p] + pw[8] * wd[5 + p];
      res[p] = s;
    }
    float4 o0 = *(const float4*)(oc + p0);
    float4 o1 = *(const float4*)(oc + p0 + 4);
    o0.x += res[0]; o0.y += res[1]; o0.z += res[2]; o0.w += res[3];
    o1.x += res[4]; o1.y += res[5]; o1.z += res[6]; o1.w += res[7];
    *(float4*)(oc + p0) = o0;
    *(float4*)(oc + p0 + 4) = o1;

    if (jc < 6) {
      um[0] = um[2]; um[1] = um[3];
      u0[0] = u0[2]; u0[1] = u0[3];
      ud[0] = ud[2]; ud[1] = ud[3];
      const int cA = p0 + 12, cB = p0 + 16;
      const bool okB = (cB < 56);
      um[2] = hasU ? *(const float4*)(rowU + cA) : Z;
      u0[2] = *(const float4*)(row0 + cA);
      ud[2] = hasD ? *(const float4*)(rowD + cA) : Z;
      um[3] = (hasU && okB) ? *(const float4*)(rowU + cB) : Z;
      u0[3] = okB ? *(const float4*)(row0 + cB) : Z;
      ud[3] = (hasD && okB) ? *(const float4*)(rowD + cB) : Z;
    }
  }
}

extern "C" void kernel_launch(void* const* d_in, const int* in_sizes, int n_in,
                              void* d_out, int out_size, void* d_ws,
                              size_t ws_size, hipStream_t stream) {
  const float* x    = (const float*)d_in[0];
  const float* qk_w = (const float*)d_in[1];
  const float* qk_b = (const float*)d_in[2];
  const float* pe_w = (const float*)d_in[3];
  const float* pe_b = (const float*)d_in[4];
  float* out = (float*)d_out;

  float* wsf = (float*)d_ws;
  float* kv7 = wsf;
  float* km7 = wsf + KM7_OFF;
  float* kvF = wsf + KVF_OFF;
  float* kmF = wsf + KMF_OFF;
  ushort* Wf = (ushort*)(wsf + WF_OFF);

  wfrag_kernel<<<32, 512, 0, stream>>>(qk_w, Wf);
  kv_kernel<<<SEV * NB, 512, 0, stream>>>(x, Wf, qk_b, kv7, km7);
  red_kernel<<<NB, 256, 0, stream>>>(kv7, km7, kvF, kmF);
  out_kernel<<<SEV * NB, 512, 0, stream>>>(x, Wf, qk_b, kvF, kmF, out);

  dim3 g3(64, NB);
  pe_kernel<<<g3, 256, 0, stream>>>(x, pe_w, pe_b, out);
}

// Round 7
// 206.794 us; speedup vs baseline: 8.1144x; 1.5037x over previous
//
#include <hip/hip_runtime.h>
#include <cmath>

#define NCH   256
#define NPIX  3136
#define NB    32
#define SEV   7
#define INV_N (1.0f / 3136.0f)

typedef __attribute__((ext_vector_type(8)))  short bf16x8;
typedef __attribute__((ext_vector_type(4)))  float f32x4;
typedef __attribute__((ext_vector_type(16))) float f32x16;

// ws layout (float offsets)
#define KV7_F  (SEV * NB * 8 * 1024)   // 1,835,008
#define KM7_F  (SEV * NB * 256)        // 57,344
#define KVF_F  (NB * 8 * 1024)         // 262,144
#define KMF_F  (NB * 256)              // 8,192
#define KM7_OFF (KV7_F)
#define KVF_OFF (KM7_OFF + KM7_F)
#define KMF_OFF (KVF_OFF + KVF_F)
#define WF_OFF  (KMF_OFF + KMF_F)      // ushort region (16B aligned)

__device__ __forceinline__ ushort f2bf(float f) {
  unsigned u = __float_as_uint(f);
  u += 0x7FFFu + ((u >> 16) & 1u);
  return (ushort)(u >> 16);
}
__device__ __forceinline__ float bf2f(ushort h) {
  return __uint_as_float(((unsigned)h) << 16);
}

// ---------------------------------------------------------------------------
// Prep: qk_w (512x128) -> MFMA A-fragment layout, bf16 hi/lo split.
// ---------------------------------------------------------------------------
__global__ void wfrag_kernel(const float* __restrict__ qk_w, ushort* __restrict__ Wf) {
  const int tid = blockIdx.x * 512 + threadIdx.x;   // 0..16383
  const int lane = tid & 63;
  const int ks = (tid >> 6) & 3;
  const int mt = (tid >> 8) & 15;
  const int hl = (tid >> 12) & 1;
  const int side = (tid >> 13) & 1;
  const int ch = mt * 16 + (lane & 15);
  const int oc = side * 256 + ch;
  ushort v[8];
#pragma unroll
  for (int j = 0; j < 8; ++j) {
    const int k = ks * 32 + (lane >> 4) * 8 + j;
    const float w = qk_w[(size_t)oc * 128 + k];
    const ushort hi = f2bf(w);
    v[j] = (hl == 0) ? hi : f2bf(w - bf2f(hi));
  }
  *(uint4*)(Wf + (size_t)tid * 8) = *(const uint4*)v;
}

// ---------------------------------------------------------------------------
// Kernel A: K-conv via MFMA (W hi/lo split), kv einsum via 32x32x16 MFMA.
// ---------------------------------------------------------------------------
__global__ __launch_bounds__(512, 2)
void kv_kernel(const float* __restrict__ x, const ushort* __restrict__ Wf,
               const float* __restrict__ qk_b, float* __restrict__ kv7,
               float* __restrict__ km7) {
  const int bid = blockIdx.x;
  const int b = bid & 31, sev = bid >> 5;
  const int t = threadIdx.x;
  const int wave = t >> 6, l = t & 63;
  const int q = l >> 4, r15 = l & 15;
  const int e = l & 31, q5 = l >> 5;
  const int mw = wave & 3, ng = wave >> 2;
  const int h = wave;

  __shared__ ushort Xb[64][136];
  __shared__ ushort Kst[256][80];
  __shared__ float kmred[256];

  bf16x8 wf[4][4][2];
#pragma unroll
  for (int mti = 0; mti < 4; ++mti)
#pragma unroll
    for (int ks = 0; ks < 4; ++ks)
#pragma unroll
      for (int hl = 0; hl < 2; ++hl) {
        const size_t off =
            (size_t)(((((2 + hl) * 16 + (mw * 4 + mti)) * 4 + ks) * 64 + l)) * 8;
        wf[mti][ks][hl] = *(const bf16x8*)(Wf + off);
      }

  float bias[4][4];
#pragma unroll
  for (int mti = 0; mti < 4; ++mti)
#pragma unroll
    for (int r = 0; r < 4; ++r)
      bias[mti][r] = qk_b[256 + (mw * 4 + mti) * 16 + q * 4 + r];

  f32x16 kvacc;
#pragma unroll
  for (int i = 0; i < 16; ++i) kvacc[i] = 0.f;
  if (t < 256) kmred[t] = 0.f;

  const float* xk = x + ((size_t)(b * NCH) + 128) * NPIX + sev * 448;
  const float* xv = x + ((size_t)(b * NCH) + h * 32 + e) * NPIX + sev * 448;

  for (int st = 0; st < SEV; ++st) {
    const int pos0 = st * 64;
#pragma unroll
    for (int rr = 0; rr < 4; ++rr) {
      const int id = t + 512 * rr;
      const int ch = id >> 4;
      const int p4 = (id & 15) * 4;
      const float4 v = *(const float4*)(xk + (size_t)ch * NPIX + pos0 + p4);
      Xb[p4 + 0][ch] = f2bf(v.x);
      Xb[p4 + 1][ch] = f2bf(v.y);
      Xb[p4 + 2][ch] = f2bf(v.z);
      Xb[p4 + 3][ch] = f2bf(v.w);
    }
    __syncthreads();

    f32x4 acc[4][2];
#pragma unroll
    for (int i = 0; i < 4; ++i)
#pragma unroll
      for (int nt = 0; nt < 2; ++nt)
#pragma unroll
        for (int r = 0; r < 4; ++r) acc[i][nt][r] = 0.f;
#pragma unroll
    for (int ks = 0; ks < 4; ++ks) {
      const bf16x8 xb0 = *(const bf16x8*)&Xb[(ng * 2 + 0) * 16 + r15][ks * 32 + q * 8];
      const bf16x8 xb1 = *(const bf16x8*)&Xb[(ng * 2 + 1) * 16 + r15][ks * 32 + q * 8];
#pragma unroll
      for (int mti = 0; mti < 4; ++mti) {
        acc[mti][0] = __builtin_amdgcn_mfma_f32_16x16x32_bf16(wf[mti][ks][0], xb0, acc[mti][0], 0, 0, 0);
        acc[mti][0] = __builtin_amdgcn_mfma_f32_16x16x32_bf16(wf[mti][ks][1], xb0, acc[mti][0], 0, 0, 0);
        acc[mti][1] = __builtin_amdgcn_mfma_f32_16x16x32_bf16(wf[mti][ks][0], xb1, acc[mti][1], 0, 0, 0);
        acc[mti][1] = __builtin_amdgcn_mfma_f32_16x16x32_bf16(wf[mti][ks][1], xb1, acc[mti][1], 0, 0, 0);
      }
    }

#pragma unroll
    for (int mti = 0; mti < 4; ++mti) {
      float kmr[4] = {0.f, 0.f, 0.f, 0.f};
#pragma unroll
      for (int nt = 0; nt < 2; ++nt) {
        const int pos = (ng * 2 + nt) * 16 + r15;
#pragma unroll
        for (int r = 0; r < 4; ++r) {
          float v = acc[mti][nt][r] + bias[mti][r];
          v = (v > 0.f) ? (v + 1.f) : __expf(v);
          kmr[r] += v;
          Kst[(mw * 4 + mti) * 16 + q * 4 + r][pos] = f2bf(v);
        }
      }
#pragma unroll
      for (int r = 0; r < 4; ++r) {
        float s = kmr[r];
        s += __shfl_xor(s, 1);
        s += __shfl_xor(s, 2);
        s += __shfl_xor(s, 4);
        s += __shfl_xor(s, 8);
        if (r15 == 0)
          atomicAdd(&kmred[(mw * 4 + mti) * 16 + q * 4 + r], s);
      }
    }
    __syncthreads();

#pragma unroll
    for (int ks = 0; ks < 4; ++ks) {
      const bf16x8 ak = *(const bf16x8*)&Kst[h * 32 + e][ks * 16 + q5 * 8];
      const float* vp = xv + pos0 + ks * 16 + q5 * 8;
      const float4 v0 = *(const float4*)vp;
      const float4 v1 = *(const float4*)(vp + 4);
      bf16x8 bv;
      bv[0] = (short)f2bf(v0.x); bv[1] = (short)f2bf(v0.y);
      bv[2] = (short)f2bf(v0.z); bv[3] = (short)f2bf(v0.w);
      bv[4] = (short)f2bf(v1.x); bv[5] = (short)f2bf(v1.y);
      bv[6] = (short)f2bf(v1.z); bv[7] = (short)f2bf(v1.w);
      kvacc = __builtin_amdgcn_mfma_f32_32x32x16_bf16(ak, bv, kvacc, 0, 0, 0);
    }
  }

  float* dst = kv7 + ((size_t)(sev * NB + b) * 8 + h) * 1024;
#pragma unroll
  for (int reg = 0; reg < 16; ++reg) {
    const int row = (reg & 3) + 8 * (reg >> 2) + 4 * q5;
    dst[row * 32 + e] = kvacc[reg];
  }
  __syncthreads();
  if (t < 256) km7[(size_t)(sev * NB + b) * 256 + t] = kmred[t];
}

// ---------------------------------------------------------------------------
// Reduce: sum 7 partials, scale by 1/n.
// ---------------------------------------------------------------------------
__global__ void red_kernel(const float* __restrict__ kv7, const float* __restrict__ km7,
                           float* __restrict__ kvF, float* __restrict__ kmF) {
  const int b = blockIdx.x;
  const int t = threadIdx.x;
  for (int i = t; i < 8192; i += 256) {
    float s = 0.f;
#pragma unroll
    for (int sv = 0; sv < SEV; ++sv)
      s += kv7[(size_t)(sv * NB + b) * 8192 + i];
    kvF[(size_t)b * 8192 + i] = s * INV_N;
  }
  {
    float s = 0.f;
#pragma unroll
    for (int sv = 0; sv < SEV; ++sv)
      s += km7[(size_t)(sv * NB + b) * 256 + t];
    kmF[b * 256 + t] = s * INV_N;
  }
}

// ---------------------------------------------------------------------------
// Kernel B: Q-conv via MFMA, num via 16x16x32 MFMA, den f32, f4 stores.
// ---------------------------------------------------------------------------
__global__ __launch_bounds__(512, 2)
void out_kernel(const float* __restrict__ x, const ushort* __restrict__ Wf,
                const float* __restrict__ qk_b, const float* __restrict__ kvF,
                const float* __restrict__ kmF, float* __restrict__ out) {
  const int bid = blockIdx.x;
  const int b = bid & 31, sev = bid >> 5;
  const int t = threadIdx.x;
  const int wave = t >> 6, l = t & 63;
  const int q = l >> 4, r15 = l & 15;
  const int mw = wave & 3, ng = wave >> 2;
  const int h = wave;

  __shared__ ushort Xb[64][136];
  __shared__ ushort QT[64][264];
  __shared__ float denT[8][64];

  bf16x8 wf[4][4][2];
#pragma unroll
  for (int mti = 0; mti < 4; ++mti)
#pragma unroll
    for (int ks = 0; ks < 4; ++ks)
#pragma unroll
      for (int hl = 0; hl < 2; ++hl) {
        const size_t off =
            (size_t)((((hl * 16 + (mw * 4 + mti)) * 4 + ks) * 64 + l)) * 8;
        wf[mti][ks][hl] = *(const bf16x8*)(Wf + off);
      }

  float bias[4][4], kmw[4][4];
#pragma unroll
  for (int mti = 0; mti < 4; ++mti)
#pragma unroll
    for (int r = 0; r < 4; ++r) {
      const int c = (mw * 4 + mti) * 16 + q * 4 + r;
      bias[mti][r] = qk_b[c];
      kmw[mti][r] = kmF[b * 256 + c];
    }

  bf16x8 bkv[2];
#pragma unroll
  for (int eh = 0; eh < 2; ++eh) {
#pragma unroll
    for (int j = 0; j < 8; ++j)
      bkv[eh][j] = (short)f2bf(
          kvF[(size_t)b * 8192 + h * 1024 + (q * 8 + j) * 32 + eh * 16 + r15]);
  }

  const float* xq = x + (size_t)(b * NCH) * NPIX + sev * 448;

  for (int st = 0; st < SEV; ++st) {
    const int pos0 = st * 64;
#pragma unroll
    for (int rr = 0; rr < 4; ++rr) {
      const int id = t + 512 * rr;
      const int ch = id >> 4;
      const int p4 = (id & 15) * 4;
      const float4 v = *(const float4*)(xq + (size_t)ch * NPIX + pos0 + p4);
      Xb[p4 + 0][ch] = f2bf(v.x);
      Xb[p4 + 1][ch] = f2bf(v.y);
      Xb[p4 + 2][ch] = f2bf(v.z);
      Xb[p4 + 3][ch] = f2bf(v.w);
    }
    __syncthreads();

    f32x4 acc[4][2];
#pragma unroll
    for (int i = 0; i < 4; ++i)
#pragma unroll
      for (int nt = 0; nt < 2; ++nt)
#pragma unroll
        for (int r = 0; r < 4; ++r) acc[i][nt][r] = 0.f;
#pragma unroll
    for (int ks = 0; ks < 4; ++ks) {
      const bf16x8 xb0 = *(const bf16x8*)&Xb[(ng * 2 + 0) * 16 + r15][ks * 32 + q * 8];
      const bf16x8 xb1 = *(const bf16x8*)&Xb[(ng * 2 + 1) * 16 + r15][ks * 32 + q * 8];
#pragma unroll
      for (int mti = 0; mti < 4; ++mti) {
        acc[mti][0] = __builtin_amdgcn_mfma_f32_16x16x32_bf16(wf[mti][ks][0], xb0, acc[mti][0], 0, 0, 0);
        acc[mti][0] = __builtin_amdgcn_mfma_f32_16x16x32_bf16(wf[mti][ks][1], xb0, acc[mti][0], 0, 0, 0);
        acc[mti][1] = __builtin_amdgcn_mfma_f32_16x16x32_bf16(wf[mti][ks][0], xb1, acc[mti][1], 0, 0, 0);
        acc[mti][1] = __builtin_amdgcn_mfma_f32_16x16x32_bf16(wf[mti][ks][1], xb1, acc[mti][1], 0, 0, 0);
      }
    }

    float pdh[2][2];
    pdh[0][0] = pdh[0][1] = pdh[1][0] = pdh[1][1] = 0.f;
#pragma unroll
    for (int mti = 0; mti < 4; ++mti) {
#pragma unroll
      for (int nt = 0; nt < 2; ++nt) {
        ushort pk[4];
        float dsum = 0.f;
#pragma unroll
        for (int r = 0; r < 4; ++r) {
          float v = acc[mti][nt][r] + bias[mti][r];
          v = (v > 0.f) ? (v + 1.f) : __expf(v);
          pk[r] = f2bf(v);
          dsum += v * kmw[mti][r];
        }
        *(uint2*)&QT[(ng * 2 + nt) * 16 + r15][(mw * 4 + mti) * 16 + q * 4] =
            *(const uint2*)pk;
        pdh[mti >> 1][nt] += dsum;
      }
    }
#pragma unroll
    for (int ht = 0; ht < 2; ++ht)
#pragma unroll
      for (int nt = 0; nt < 2; ++nt) {
        float s = pdh[ht][nt];
        s += __shfl_xor(s, 16);
        s += __shfl_xor(s, 32);
        if (q == 0) denT[mw * 2 + ht][(ng * 2 + nt) * 16 + r15] = s;
      }
    __syncthreads();

#pragma unroll
    for (int pt = 0; pt < 4; ++pt) {
      const bf16x8 aq = *(const bf16x8*)&QT[pt * 16 + r15][h * 32 + q * 8];
      f32x4 z;
      z[0] = z[1] = z[2] = z[3] = 0.f;
      const f32x4 n0 = __builtin_amdgcn_mfma_f32_16x16x32_bf16(aq, bkv[0], z, 0, 0, 0);
      const f32x4 n1 = __builtin_amdgcn_mfma_f32_16x16x32_bf16(aq, bkv[1], z, 0, 0, 0);
      float4 o0, o1;
      float rdn[4];
#pragma unroll
      for (int r = 0; r < 4; ++r)
        rdn[r] = 1.0f / (denT[h][pt * 16 + q * 4 + r] + 1e-6f);
      o0.x = n0[0] * rdn[0]; o0.y = n0[1] * rdn[1];
      o0.z = n0[2] * rdn[2]; o0.w = n0[3] * rdn[3];
      o1.x = n1[0] * rdn[0]; o1.y = n1[1] * rdn[1];
      o1.z = n1[2] * rdn[2]; o1.w = n1[3] * rdn[3];
      const int posg = sev * 448 + pos0 + pt * 16 + q * 4;
      const int c0 = h * 32 + r15;
      const int c1 = h * 32 + 16 + r15;
      *(float4*)(out + ((size_t)(b * NCH + c0)) * NPIX + posg) = o0;
      *(float4*)(out + ((size_t)(b * NCH + c1)) * NPIX + posg) = o1;
    }
  }
}

// ---------------------------------------------------------------------------
// Kernel C (rewritten): depthwise 3x3 pe conv, added into out (RMW).
// Block = (b, 4 channels). Full channel images staged in LDS via coalesced
// f4 loads (x read exactly once). Compute maps lane->column so the out RMW
// is contiguous 224B/wave; rows processed in groups of 4 for MLP.
// ---------------------------------------------------------------------------
__global__ __launch_bounds__(256)
void pe_kernel(const float* __restrict__ x, const float* __restrict__ pe_w,
               const float* __restrict__ pe_b, float* __restrict__ out) {
  const int b = blockIdx.y;
  const int c0 = blockIdx.x * 4;
  const int t = threadIdx.x;
  const int cl = t >> 6;        // 0..3: wave -> channel
  const int lane = t & 63;      // lane -> column (56 active)

  __shared__ float xs[4][NPIX];   // 50 KB

  // stage 4 channel images, coalesced float4
#pragma unroll
  for (int cc = 0; cc < 4; ++cc) {
    const float4* src = (const float4*)(x + ((size_t)(b * NCH + c0 + cc)) * NPIX);
    float4* dst = (float4*)&xs[cc][0];
    for (int i = t; i < NPIX / 4; i += 256) dst[i] = src[i];
  }
  __syncthreads();

  const int c = c0 + cl;
  float pw[9];
#pragma unroll
  for (int i = 0; i < 9; ++i) pw[i] = pe_w[c * 9 + i];
  const float pb = pe_b[c];
  float* oc = out + ((size_t)(b * NCH + c)) * NPIX;
  const float* xc = xs[cl];

  if (lane < 56) {
    const bool hasL = (lane > 0), hasR = (lane < 55);
    for (int rg = 0; rg < 14; ++rg) {
      // 4 independent out reads (coalesced 224B/wave each)
      float o[4];
#pragma unroll
      for (int k = 0; k < 4; ++k) o[k] = oc[(rg * 4 + k) * 56 + lane];
#pragma unroll
      for (int k = 0; k < 4; ++k) {
        const int r = rg * 4 + k;
        float s = pb;
#pragma unroll
        for (int dy = -1; dy <= 1; ++dy) {
          const int rr = r + dy;
          if (rr < 0 || rr >= 56) continue;   // wave-uniform
          const float* xrow = xc + rr * 56 + lane;
          if (hasL) s += pw[(dy + 1) * 3 + 0] * xrow[-1];
          s += pw[(dy + 1) * 3 + 1] * xrow[0];
          if (hasR) s += pw[(dy + 1) * 3 + 2] * xrow[1];
        }
        o[k] += s;
      }
#pragma unroll
      for (int k = 0; k < 4; ++k) oc[(rg * 4 + k) * 56 + lane] = o[k];
    }
  }
}

extern "C" void kernel_launch(void* const* d_in, const int* in_sizes, int n_in,
                              void* d_out, int out_size, void* d_ws,
                              size_t ws_size, hipStream_t stream) {
  const float* x    = (const float*)d_in[0];
  const float* qk_w = (const float*)d_in[1];
  const float* qk_b = (const float*)d_in[2];
  const float* pe_w = (const float*)d_in[3];
  const float* pe_b = (const float*)d_in[4];
  float* out = (float*)d_out;

  float* wsf = (float*)d_ws;
  float* kv7 = wsf;
  float* km7 = wsf + KM7_OFF;
  float* kvF = wsf + KVF_OFF;
  float* kmF = wsf + KMF_OFF;
  ushort* Wf = (ushort*)(wsf + WF_OFF);

  wfrag_kernel<<<32, 512, 0, stream>>>(qk_w, Wf);
  kv_kernel<<<SEV * NB, 512, 0, stream>>>(x, Wf, qk_b, kv7, km7);
  red_kernel<<<NB, 256, 0, stream>>>(kv7, km7, kvF, kmF);
  out_kernel<<<SEV * NB, 512, 0, stream>>>(x, Wf, qk_b, kvF, kmF, out);

  dim3 g3(64, NB);
  pe_kernel<<<g3, 256, 0, stream>>>(x, pe_w, pe_b, out);
}